// Round 5
// baseline (282.898 us; speedup 1.0000x reference)
//
#include <hip/hip_runtime.h>
#include <hip/hip_bf16.h>

// Problem constants
#define NB 256
#define NACT 21
#define NA 8192
#define NE 262144
#define CSR_CAP 128  // max in-degree capacity (Poisson(32) tail beyond 128 ~ 1e-14)
#define NBLK 256
#define NTHR 512

typedef __attribute__((ext_vector_type(8))) short short8;
typedef __attribute__((ext_vector_type(4))) float float4v;

__device__ inline float wsum64(float v) {
#pragma unroll
  for (int m = 32; m > 0; m >>= 1) v += __shfl_xor(v, m, 64);
  return v;
}

__device__ inline unsigned short f2bf(float f) {
  union { __hip_bfloat16 h; unsigned short u; } cv;
  cv.h = __float2bfloat16(f);
  return cv.u;
}

// Grid barrier: per-phase counter (zeroed by k_init), release-add + acquire-spin.
// Bounded spin: if co-residency/coherence ever breaks we produce wrong results
// instead of hanging the harness.
__device__ inline void gridbar(int* bar, int idx) {
  __syncthreads();
  if (threadIdx.x == 0) {
    __threadfence();  // agent-scope release (L2 writeback on gfx950)
    __hip_atomic_fetch_add(&bar[idx], 1, __ATOMIC_RELEASE, __HIP_MEMORY_SCOPE_AGENT);
    int guard = 0;
    while (__hip_atomic_load(&bar[idx], __ATOMIC_ACQUIRE, __HIP_MEMORY_SCOPE_AGENT) < NBLK &&
           guard < (1 << 22)) {
      guard++;
      __builtin_amdgcn_s_sleep(2);
    }
  }
  __syncthreads();
}

// ---------------- dispatch 1: zero state + action passthrough ----------------
__global__ void k_init(const int* action, float* hidden, int* cnt, float* wstats, int* bar,
                       float* out) {
  int i = blockIdx.x * 256 + threadIdx.x;  // 131072 threads
  hidden[i] = 0.0f;
  if (i < NA) cnt[i] = 0;
  if (i < 32) wstats[i] = 0.0f;
  if (i < 16) bar[i] = 0;
  if (i < NB) out[i] = (float)action[i];
}

// ---------------- dispatch 2: everything else ----------------
__global__ __launch_bounds__(NTHR, 2) void k_mega(
    const float* __restrict__ x, const float* __restrict__ x_msg,
    const int* __restrict__ edges,
    const float* __restrict__ c1w, const float* __restrict__ c1b,
    const float* __restrict__ c2w, const float* __restrict__ c2b,
    const float* __restrict__ fcw, const float* __restrict__ fcb,
    const float* __restrict__ muw, const float* __restrict__ mub,
    const float* __restrict__ msgw, const float* __restrict__ msgb,
    const float* __restrict__ g1w, const float* __restrict__ g1b,
    const float* __restrict__ g2w, const float* __restrict__ g2b,
    const int* __restrict__ action,
    float* h1024, float* gbuf, float* hidden, float* enc0, float* dinv, float* wstats,
    unsigned short* w2t, int* cnt, int* csr, int* bar, float* out) {
  union SM {
    struct { float xs[845]; float w1s[1440]; float c1s[1152]; float w2s[64 * 73]; } cv;
    struct { float At[32][68]; float Bt[32][68]; } fc;
    struct { float muT[512 * 21]; float hrows[2048]; } hd;
    struct { float red[32][17]; float b2s[32]; } w2;
    struct { unsigned short vbf[512]; float vf[512]; float pl[4096]; float sl[256]; } mg;
  };
  __shared__ __align__(16) union SM sm;
  int t = threadIdx.x, blk = blockIdx.x;
  int wave = t >> 6, lane = t & 63;
  int gid = blk * NTHR + t;  // 0..131071

  //================ P0: CSR build + W2 prep + conv ================
  {  // CSR: 2 edges per thread, counting-sort by dst
    int e = gid;
    int s = edges[2 * e], d = edges[2 * e + 1];
    int slot = atomicAdd(&cnt[d], 1);
    if (slot < CSR_CAP) csr[d * CSR_CAP + slot] = s;
    e = gid + 131072;
    s = edges[2 * e]; d = edges[2 * e + 1];
    slot = atomicAdd(&cnt[d], 1);
    if (slot < CSR_CAP) csr[d * CSR_CAP + slot] = s;
  }
  {  // W2 transpose->bf16 + column sums + bias sum (block covers 32 cols)
    int jj = t >> 4, k = t & 15;
    int j = blk * 32 + jj;
    float w = g2w[k * 8192 + j];
    w2t[j * 16 + k] = f2bf(w);
    sm.w2.red[jj][k] = w;
    if (t < 32) sm.w2.b2s[t] = g2b[blk * 32 + t];
    __syncthreads();
    if (t < 16) {
      float s = 0.0f;
#pragma unroll
      for (int q = 0; q < 32; q++) s += sm.w2.red[q][t];
      atomicAdd(&wstats[t], s);
    } else if (t == 16) {
      float s = 0.0f;
#pragma unroll
      for (int q = 0; q < 32; q++) s += sm.w2.b2s[q];
      atomicAdd(&wstats[16], s);
    }
    __syncthreads();
  }
  {  // fused conv1+conv2, one block per image
    for (int i = t; i < 845; i += NTHR) sm.cv.xs[i] = x[blk * 845 + i];
    for (int i = t; i < 1440; i += NTHR) sm.cv.w1s[i] = c1w[i];
    __syncthreads();
    for (int idx = t; idx < 1152; idx += NTHR) {
      int oc = idx / 36, p = idx - oc * 36;
      int oy = p / 6, ox = p - oy * 6;
      float acc = c1b[oc];
      const float* wp = &sm.cv.w1s[oc * 45];
#pragma unroll
      for (int ic = 0; ic < 5; ic++)
#pragma unroll
        for (int ky = 0; ky < 3; ky++)
#pragma unroll
          for (int kx = 0; kx < 3; kx++)
            acc += sm.cv.xs[ic * 169 + (oy * 2 + ky) * 13 + ox * 2 + kx] * wp[ic * 9 + ky * 3 + kx];
      sm.cv.c1s[idx] = fmaxf(acc, 0.0f);
    }
    int p = t & 15, oc2 = t >> 4;  // oc2 0..31, each handles 2 output channels
    int oy = p >> 2, ox = p & 3;
    float a0 = c2b[oc2 * 2 + 0], a1 = c2b[oc2 * 2 + 1];
    for (int icb = 0; icb < 32; icb += 8) {
      __syncthreads();
      for (int i = t; i < 4608; i += NTHR) {
        int oc = i / 72, r = i - oc * 72;
        sm.cv.w2s[oc * 73 + r] = c2w[oc * 288 + icb * 9 + r];
      }
      __syncthreads();
#pragma unroll
      for (int ic = 0; ic < 8; ic++) {
#pragma unroll
        for (int ky = 0; ky < 3; ky++) {
#pragma unroll
          for (int kx = 0; kx < 3; kx++) {
            float cvv = sm.cv.c1s[(icb + ic) * 36 + (oy + ky) * 6 + ox + kx];
            int wi = ic * 9 + ky * 3 + kx;
            a0 += cvv * sm.cv.w2s[(oc2 * 2 + 0) * 73 + wi];
            a1 += cvv * sm.cv.w2s[(oc2 * 2 + 1) * 73 + wi];
          }
        }
      }
    }
    float* hp = &h1024[blk * 1024];
    hp[(oc2 * 2 + 0) * 16 + p] = fmaxf(a0, 0.0f);
    hp[(oc2 * 2 + 1) * 16 + p] = fmaxf(a1, 0.0f);
  }
  gridbar(bar, 0);

  //================ P1: dinv + FC GEMM (K-split 8, atomic accumulate) ================
  if (gid < NA) dinv[gid] = rsqrtf((float)cnt[gid] + 1.0f);
  {
    int kz = blk & 7, cbi = (blk >> 3) & 7, rbi = blk >> 6;  // 8 K-slices x 8 N x 4 M
    int rb = rbi * 64, cb = cbi * 64, kb = kz * 128;
    int sr = t >> 3, skq = (t & 7) * 4;
    int tx = t & 15, tyy = t >> 4;  // 16 col-groups x 32 row-groups
    float acc[2][4] = {{0}};
    for (int kc = 0; kc < 128; kc += 32) {
      float4 av = *(const float4*)&h1024[(rb + sr) * 1024 + kb + kc + skq];
      float4 bv = *(const float4*)&fcw[(cb + sr) * 1024 + kb + kc + skq];
      __syncthreads();
      sm.fc.At[skq + 0][sr] = av.x; sm.fc.At[skq + 1][sr] = av.y;
      sm.fc.At[skq + 2][sr] = av.z; sm.fc.At[skq + 3][sr] = av.w;
      sm.fc.Bt[skq + 0][sr] = bv.x; sm.fc.Bt[skq + 1][sr] = bv.y;
      sm.fc.Bt[skq + 2][sr] = bv.z; sm.fc.Bt[skq + 3][sr] = bv.w;
      __syncthreads();
#pragma unroll
      for (int k = 0; k < 32; k++) {
        float aa0 = sm.fc.At[k][tyy * 2], aa1 = sm.fc.At[k][tyy * 2 + 1];
        float4 b4 = *(const float4*)&sm.fc.Bt[k][tx * 4];
        acc[0][0] += aa0 * b4.x; acc[0][1] += aa0 * b4.y; acc[0][2] += aa0 * b4.z; acc[0][3] += aa0 * b4.w;
        acc[1][0] += aa1 * b4.x; acc[1][1] += aa1 * b4.y; acc[1][2] += aa1 * b4.z; acc[1][3] += aa1 * b4.w;
      }
    }
#pragma unroll
    for (int i = 0; i < 2; i++)
#pragma unroll
      for (int j = 0; j < 4; j++)
        atomicAdd(&hidden[(rb + tyy * 2 + i) * 512 + cb + tx * 4 + j], acc[i][j]);
  }
  gridbar(bar, 1);

  //================ P2: FC bias + relu ================
  hidden[gid] = fmaxf(hidden[gid] + fcb[gid & 511], 0.0f);
  gridbar(bar, 2);

  //================ P3: head (blocks 0..63) | enc0 (blocks 64..255) ================
  if (blk < 64) {
    int b0 = blk * 4;
    for (int i = t; i < 10752; i += NTHR) {
      int a = i >> 9, k = i & 511;
      sm.hd.muT[k * 21 + a] = muw[i];
    }
    for (int i = t; i < 2048; i += NTHR) sm.hd.hrows[i] = hidden[b0 * 512 + i];
    __syncthreads();
    if (wave < 4) {
      int b = b0 + wave;
      float logit = -1e30f;
      if (lane < NACT) {
        float acc = mub[lane];
        const float* hr = &sm.hd.hrows[wave * 512];
        for (int k = 0; k < 512; k++) acc += hr[k] * sm.hd.muT[k * 21 + lane];
        logit = acc;
      }
      float m = logit;
#pragma unroll
      for (int s = 32; s > 0; s >>= 1) m = fmaxf(m, __shfl_xor(m, s, 64));
      float e = (lane < NACT) ? __expf(logit - m) : 0.0f;
      float se = wsum64(e);
      float swl = wsum64(e * logit);
      float lse = m + __logf(se);
      int act = action[b];
      if (lane == 0) out[8704 + b] = lse - swl / se;   // entropy
      if (lane == act) out[8448 + b] = logit - lse;    // log_prob
    }
  } else {
    int wg = (blk - 64) * 8 + wave;  // 0..1535
    for (int j = wg; j < NA; j += 1536) {
      const float* wp = &msgw[j * 512 + lane * 8];
      float4 w0 = *(const float4*)(wp);
      float4 w1 = *(const float4*)(wp + 4);
      float4 h0 = *(const float4*)&hidden[lane * 8];
      float4 h1 = *(const float4*)&hidden[lane * 8 + 4];
      float s = w0.x * h0.x + w0.y * h0.y + w0.z * h0.z + w0.w * h0.w +
                w1.x * h1.x + w1.y * h1.y + w1.z * h1.z + w1.w * h1.w;
      s = wsum64(s);
      if (lane == 0) enc0[j] = s + msgb[j];
    }
  }
  gridbar(bar, 3);

  //================ P4: GCN1 gather (4 rows per wave) ================
  {
    int wg = blk * 8 + wave;  // 0..2047
#pragma unroll
    for (int rr = 0; rr < 4; rr++) {
      int i = wg * 4 + rr;
      int ci = min(cnt[i], CSR_CAP);
      float di = dinv[i];
      float a0 = 0.0f, a1 = 0.0f;
      for (int e = lane; e < ci; e += 64) {
        int s = csr[i * CSR_CAP + e];
        float w = dinv[s];
        a0 += w * x_msg[s];
        a1 += w * enc0[s];
      }
      a0 = wsum64(a0) * di + di * di * x_msg[i];
      a1 = wsum64(a1) * di + di * di * enc0[i];
      if (lane < 16)
        gbuf[i * 16 + lane] = fmaxf(a0 * g1w[lane] + a1 * g1w[16 + lane] + g1b[lane], 0.0f);
    }
  }
  gridbar(bar, 4);

  //================ P5: GCN2 gather + V.W2 scores (MFMA) + sum-exp + mean ================
  {
    int rowbase = blk * 32;
    {  // gather V rows: wave handles 4 rows; lanes = 4 edge-groups x 16 cols
      int eq = lane >> 4, c = lane & 15;
#pragma unroll
      for (int rr = 0; rr < 4; rr++) {
        int il = wave * 4 + rr;
        int i = rowbase + il;
        int ci = min(cnt[i], CSR_CAP);
        float di = dinv[i];
        float acc = (eq == 0) ? di * gbuf[i * 16 + c] : 0.0f;  // self-loop: di^2 after *=di
        for (int e = eq; e < ci; e += 4) {
          int s = csr[i * CSR_CAP + e];
          acc += dinv[s] * gbuf[s * 16 + c];
        }
        acc *= di;
        acc += __shfl_xor(acc, 16, 64);
        acc += __shfl_xor(acc, 32, 64);
        if (eq == 0) {
          sm.mg.vf[il * 16 + c] = acc;
          sm.mg.vbf[il * 16 + c] = f2bf(acc);
        }
      }
    }
    __syncthreads();
    float myMean = 0.0f;
    if (t < 32) {
      float dot = 0.0f;
#pragma unroll
      for (int c = 0; c < 16; c++) dot += sm.mg.vf[t * 16 + c] * wstats[c];
      myMean = (dot + wstats[16]) * (1.0f / 8192.0f);  // exact fp32 mean_j
    }
    int quad = lane >> 4, n = lane & 15;
    int k8 = quad * 8;
    short8 za = {0, 0, 0, 0, 0, 0, 0, 0};
    short8 a1 = za, a2 = za;
    if (quad < 2) {  // K padded 16->32: upper-K quads hold zeros on both operands
      a1 = *(const short8*)&sm.mg.vbf[n * 16 + k8];
      a2 = *(const short8*)&sm.mg.vbf[(16 + n) * 16 + k8];
    }
    float sacc[8];
#pragma unroll
    for (int q = 0; q < 8; q++) sacc[q] = 0.0f;
    int colb = wave * 1024 + n;
    for (int tp = 0; tp < 64; tp += 2) {
      int col1 = colb + tp * 16;
      int col2 = col1 + 16;
      short8 b1 = za, b2 = za;
      if (quad < 2) {
        b1 = *(const short8*)&w2t[col1 * 16 + k8];
        b2 = *(const short8*)&w2t[col2 * 16 + k8];
      }
      float bb1 = g2b[col1], bb2 = g2b[col2];
      float4v c1 = {bb1, bb1, bb1, bb1};
      float4v c2 = {bb2, bb2, bb2, bb2};
      float4v s11 = __builtin_amdgcn_mfma_f32_16x16x32_bf16(a1, b1, c1, 0, 0, 0);
      float4v s21 = __builtin_amdgcn_mfma_f32_16x16x32_bf16(a2, b1, c1, 0, 0, 0);
      float4v s12 = __builtin_amdgcn_mfma_f32_16x16x32_bf16(a1, b2, c2, 0, 0, 0);
      float4v s22 = __builtin_amdgcn_mfma_f32_16x16x32_bf16(a2, b2, c2, 0, 0, 0);
#pragma unroll
      for (int r = 0; r < 4; r++) {
        sacc[r]     += __expf(s11[r]) + __expf(s12[r]);
        sacc[4 + r] += __expf(s21[r]) + __expf(s22[r]);
      }
    }
#pragma unroll
    for (int q = 0; q < 8; q++) {
      int rl = (q >> 2) * 16 + quad * 4 + (q & 3);  // C/D row = quad*4+reg (+16 for A2 block)
      int cc = wave * 16 + n;
      sm.mg.pl[rl * 128 + cc] = sacc[q];
    }
    __syncthreads();
    if (t < 256) {
      int r = t >> 3, seg = t & 7;
      int base = r * 128 + seg * 16;
      float ll = 0.0f;
#pragma unroll
      for (int i = 0; i < 16; i++) ll += sm.mg.pl[base + i];
      sm.mg.sl[r * 8 + seg] = ll;
    }
    __syncthreads();
    if (t < 32) {
      float ll = 0.0f;
#pragma unroll
      for (int i = 0; i < 8; i++) ll += sm.mg.sl[t * 8 + i];
      out[256 + rowbase + t] = myMean - __logf(ll);
    }
  }
}

extern "C" void kernel_launch(void* const* d_in, const int* in_sizes, int n_in,
                              void* d_out, int out_size, void* d_ws, size_t ws_size,
                              hipStream_t stream) {
  const float* x     = (const float*)d_in[0];
  const float* x_msg = (const float*)d_in[1];
  const int*   edges = (const int*)d_in[2];
  const int*   action= (const int*)d_in[3];
  const float* c1w   = (const float*)d_in[4];
  const float* c1b   = (const float*)d_in[5];
  const float* c2w   = (const float*)d_in[6];
  const float* c2b   = (const float*)d_in[7];
  const float* fcw   = (const float*)d_in[8];
  const float* fcb   = (const float*)d_in[9];
  const float* muw   = (const float*)d_in[10];
  const float* mub   = (const float*)d_in[11];
  const float* msgw  = (const float*)d_in[12];
  const float* msgb  = (const float*)d_in[13];
  const float* g1w   = (const float*)d_in[14];
  const float* g1b   = (const float*)d_in[15];
  const float* g2w   = (const float*)d_in[16];
  const float* g2b   = (const float*)d_in[17];
  float* out = (float*)d_out;  // reference outputs are fp32

  // Workspace (floats). gbuf aliases h1024[0:131072) (h1024 dead after FC phase).
  float* ws     = (float*)d_ws;
  float* h1024  = ws;                    // [0, 262144)
  float* gbuf   = ws;                    // alias, [0, 131072)
  float* hidden = ws + 262144;           // 131072
  float* enc0   = ws + 393216;           // 8192
  float* dinv   = ws + 401408;           // 8192
  float* wstats = ws + 409600;           // 32
  unsigned short* w2t = (unsigned short*)(ws + 409632);  // 131072 bf16 = 65536 floats
  int*   cnt    = (int*)(ws + 475168);   // 8192
  int*   csr    = (int*)(ws + 483360);   // 8192*128 = 1048576 ints
  int*   bar    = (int*)(ws + 1531936);  // 16  -> total ~6.1 MB

  k_init<<<512, 256, 0, stream>>>(action, hidden, cnt, wstats, bar, out);
  k_mega<<<NBLK, NTHR, 0, stream>>>(x, x_msg, edges, c1w, c1b, c2w, c2b, fcw, fcb,
                                    muw, mub, msgw, msgb, g1w, g1b, g2w, g2b, action,
                                    h1024, gbuf, hidden, enc0, dinv, wstats,
                                    w2t, cnt, csr, bar, out);
}

// Round 6
// 222.554 us; speedup vs baseline: 1.2711x; 1.2711x over previous
//
#include <hip/hip_runtime.h>
#include <hip/hip_bf16.h>

// Problem constants
#define NB 256
#define NACT 21
#define NA 8192
#define NE 262144
#define CSR_CAP 128
#define NBLK 256
#define NTHR 512

typedef __attribute__((ext_vector_type(8))) short short8;
typedef __attribute__((ext_vector_type(4))) float float4v;

__device__ inline float wsum64(float v) {
#pragma unroll
  for (int m = 32; m > 0; m >>= 1) v += __shfl_xor(v, m, 64);
  return v;
}

__device__ inline unsigned short f2bf(float f) {
  union { __hip_bfloat16 h; unsigned short u; } cv;
  cv.h = __float2bfloat16(f);
  return cv.u;
}

// Grid barrier: release-add, RELAXED poll (no per-poll L2 invalidate), one
// final acquire. Bounded spin -> wrong results instead of hang on failure.
__device__ inline void gridbar(int* bar, int idx) {
  __syncthreads();
  if (threadIdx.x == 0) {
    __hip_atomic_fetch_add(&bar[idx], 1, __ATOMIC_RELEASE, __HIP_MEMORY_SCOPE_AGENT);
    int guard = 0;
    while (__hip_atomic_load(&bar[idx], __ATOMIC_RELAXED, __HIP_MEMORY_SCOPE_AGENT) < NBLK &&
           guard < (1 << 22)) {
      guard++;
      __builtin_amdgcn_s_sleep(8);
    }
    (void)__hip_atomic_load(&bar[idx], __ATOMIC_ACQUIRE, __HIP_MEMORY_SCOPE_AGENT);
  }
  __syncthreads();
}

// ---------------- dispatch 1: zero cnt/bar + action passthrough ----------------
__global__ void k_init(const int* action, int* cnt, int* bar, float* out) {
  int i = blockIdx.x * 256 + threadIdx.x;  // 33*256 = 8448 threads
  if (i < NA) cnt[i] = 0;
  if (i < 16) bar[i] = 0;
  if (i < NB) out[i] = (float)action[i];
}

// ---------------- kA: CSR build + W2 prep (partials) + conv ----------------
__global__ __launch_bounds__(NTHR, 2) void kA(
    const float* __restrict__ x, const int* __restrict__ edges,
    const float* __restrict__ c1w, const float* __restrict__ c1b,
    const float* __restrict__ c2w, const float* __restrict__ c2b,
    const float* __restrict__ g2w, const float* __restrict__ g2b,
    float* h1024, unsigned short* w2t, float* wpart, int* cnt, int* csr) {
  union SM {
    struct { float xs[845]; float w1s[1440]; float c1s[1152]; float w2s[64 * 73]; } cv;
    struct { float red[32][17]; float b2s[32]; } w2;
  };
  __shared__ __align__(16) union SM sm;
  int t = threadIdx.x, blk = blockIdx.x;
  int gid = blk * NTHR + t;

  {  // CSR: 2 edges per thread, counting-sort by dst
    int e = gid;
    int s = edges[2 * e], d = edges[2 * e + 1];
    int slot = atomicAdd(&cnt[d], 1);
    if (slot < CSR_CAP) csr[d * CSR_CAP + slot] = s;
    e = gid + 131072;
    s = edges[2 * e]; d = edges[2 * e + 1];
    slot = atomicAdd(&cnt[d], 1);
    if (slot < CSR_CAP) csr[d * CSR_CAP + slot] = s;
  }
  {  // W2 transpose->bf16 + per-block column/bias partial sums (no atomics)
    int jj = t >> 4, k = t & 15;
    int j = blk * 32 + jj;
    float w = g2w[k * 8192 + j];
    w2t[j * 16 + k] = f2bf(w);
    sm.w2.red[jj][k] = w;
    if (t < 32) sm.w2.b2s[t] = g2b[blk * 32 + t];
    __syncthreads();
    if (t < 16) {
      float s = 0.0f;
#pragma unroll
      for (int q = 0; q < 32; q++) s += sm.w2.red[q][t];
      wpart[blk * 17 + t] = s;
    } else if (t == 16) {
      float s = 0.0f;
#pragma unroll
      for (int q = 0; q < 32; q++) s += sm.w2.b2s[q];
      wpart[blk * 17 + 16] = s;
    }
    __syncthreads();
  }
  {  // fused conv1+conv2, one block per image
    for (int i = t; i < 845; i += NTHR) sm.cv.xs[i] = x[blk * 845 + i];
    for (int i = t; i < 1440; i += NTHR) sm.cv.w1s[i] = c1w[i];
    __syncthreads();
    for (int idx = t; idx < 1152; idx += NTHR) {
      int oc = idx / 36, p = idx - oc * 36;
      int oy = p / 6, ox = p - oy * 6;
      float acc = c1b[oc];
      const float* wp = &sm.cv.w1s[oc * 45];
#pragma unroll
      for (int ic = 0; ic < 5; ic++)
#pragma unroll
        for (int ky = 0; ky < 3; ky++)
#pragma unroll
          for (int kx = 0; kx < 3; kx++)
            acc += sm.cv.xs[ic * 169 + (oy * 2 + ky) * 13 + ox * 2 + kx] * wp[ic * 9 + ky * 3 + kx];
      sm.cv.c1s[idx] = fmaxf(acc, 0.0f);
    }
    int p = t & 15, oc2 = t >> 4;  // oc2 0..31, 2 output channels each
    int oy = p >> 2, ox = p & 3;
    float a0 = c2b[oc2 * 2 + 0], a1 = c2b[oc2 * 2 + 1];
    for (int icb = 0; icb < 32; icb += 8) {
      __syncthreads();
      for (int i = t; i < 4608; i += NTHR) {
        int oc = i / 72, r = i - oc * 72;
        sm.cv.w2s[oc * 73 + r] = c2w[oc * 288 + icb * 9 + r];
      }
      __syncthreads();
#pragma unroll
      for (int ic = 0; ic < 8; ic++) {
#pragma unroll
        for (int ky = 0; ky < 3; ky++) {
#pragma unroll
          for (int kx = 0; kx < 3; kx++) {
            float cvv = sm.cv.c1s[(icb + ic) * 36 + (oy + ky) * 6 + ox + kx];
            int wi = ic * 9 + ky * 3 + kx;
            a0 += cvv * sm.cv.w2s[(oc2 * 2 + 0) * 73 + wi];
            a1 += cvv * sm.cv.w2s[(oc2 * 2 + 1) * 73 + wi];
          }
        }
      }
    }
    float* hp = &h1024[blk * 1024];
    hp[(oc2 * 2 + 0) * 16 + p] = fmaxf(a0, 0.0f);
    hp[(oc2 * 2 + 1) * 16 + p] = fmaxf(a1, 0.0f);
  }
}

// ---------------- kB: dinv/xs2 + FC (single-writer) | bar | head + enc ----------------
__global__ __launch_bounds__(NTHR, 2) void kB(
    const int* __restrict__ cnt, const float* __restrict__ x_msg,
    const float* __restrict__ h1024, const float* __restrict__ fcw,
    const float* __restrict__ fcb, const float* __restrict__ muw,
    const float* __restrict__ mub, const int* __restrict__ action,
    const float* __restrict__ msgw, const float* __restrict__ msgb,
    float* hidden, float* dinv, float* xs2, float* es2, int* bar, float* out) {
  union SM {
    struct { float As[16][132]; float Bs[32][132]; } fc;
    struct { float muT[512 * 21]; float hrows[2048]; } hd;
  };
  __shared__ __align__(16) union SM sm;
  int t = threadIdx.x, blk = blockIdx.x;
  int wave = t >> 6, lane = t & 63;
  int gid = blk * NTHR + t;

  if (gid < NA) {
    float d = rsqrtf((float)cnt[gid] + 1.0f);
    dinv[gid] = d;
    xs2[gid] = d * x_msg[gid];
  }
  {  // FC: block owns 16x32 output tile; K=1024 in chunks of 128. No atomics.
    int rb = (blk >> 4) * 16, cb = (blk & 15) * 32;
    int r = t >> 5, c = t & 31;
    float acc = 0.0f;
    for (int kb = 0; kb < 1024; kb += 128) {
      __syncthreads();
      {  // stage A 16x128 (4 floats/thread), B 32x128 (8 floats/thread)
        int idx = t * 4;
        int ar = idx >> 7, ak = idx & 127;
        *(float4*)&sm.fc.As[ar][ak] = *(const float4*)&h1024[(rb + ar) * 1024 + kb + ak];
        int idb = t * 8;
        int br = idb >> 7, bk = idb & 127;
        *(float4*)&sm.fc.Bs[br][bk] = *(const float4*)&fcw[(cb + br) * 1024 + kb + bk];
        *(float4*)&sm.fc.Bs[br][bk + 4] = *(const float4*)&fcw[(cb + br) * 1024 + kb + bk + 4];
      }
      __syncthreads();
#pragma unroll 8
      for (int kk = 0; kk < 128; kk += 4) {
        float4 a = *(const float4*)&sm.fc.As[r][kk];
        float4 b = *(const float4*)&sm.fc.Bs[c][kk];
        acc += a.x * b.x + a.y * b.y + a.z * b.z + a.w * b.w;
      }
    }
    hidden[(rb + r) * 512 + cb + c] = fmaxf(acc + fcb[cb + c], 0.0f);
  }
  gridbar(bar, 0);
  if (blk < 64) {  // head: 4 batch rows per block
    int b0 = blk * 4;
    for (int i = t; i < 10752; i += NTHR) {
      int a = i >> 9, k = i & 511;
      sm.hd.muT[k * 21 + a] = muw[i];
    }
    for (int i = t; i < 2048; i += NTHR) sm.hd.hrows[i] = hidden[b0 * 512 + i];
    __syncthreads();
    if (wave < 4) {
      int b = b0 + wave;
      float logit = -1e30f;
      if (lane < NACT) {
        float acc = mub[lane];
        const float* hr = &sm.hd.hrows[wave * 512];
        for (int k = 0; k < 512; k++) acc += hr[k] * sm.hd.muT[k * 21 + lane];
        logit = acc;
      }
      float m = logit;
#pragma unroll
      for (int s = 32; s > 0; s >>= 1) m = fmaxf(m, __shfl_xor(m, s, 64));
      float e = (lane < NACT) ? __expf(logit - m) : 0.0f;
      float se = wsum64(e);
      float swl = wsum64(e * logit);
      float lse = m + __logf(se);
      int act = action[b];
      if (lane == 0) out[8704 + b] = lse - swl / se;   // entropy
      if (lane == act) out[8448 + b] = logit - lse;    // log_prob
    }
  } else {  // enc: es2[j] = dinv[j] * (hidden[0].msg_w[j] + msgb[j])
    int wg = (blk - 64) * 8 + wave;  // 0..1535
    for (int j = wg; j < NA; j += 1536) {
      const float* wp = &msgw[j * 512 + lane * 8];
      float4 w0 = *(const float4*)(wp);
      float4 w1 = *(const float4*)(wp + 4);
      float4 h0 = *(const float4*)&hidden[lane * 8];
      float4 h1 = *(const float4*)&hidden[lane * 8 + 4];
      float s = w0.x * h0.x + w0.y * h0.y + w0.z * h0.z + w0.w * h0.w +
                w1.x * h1.x + w1.y * h1.y + w1.z * h1.z + w1.w * h1.w;
      s = wsum64(s);
      if (lane == 0) es2[j] = dinv[j] * (s + msgb[j]);
    }
  }
}

// ---------------- kC: GCN1 (prescaled) | bar | wstats-reduce + GCN2 + MFMA + msg ----------------
__global__ __launch_bounds__(NTHR, 2) void kC(
    const int* __restrict__ cnt, const int* __restrict__ csr,
    const float* __restrict__ dinv, const float* __restrict__ xs2,
    const float* __restrict__ es2, const float* __restrict__ g1w,
    const float* __restrict__ g1b, const float* __restrict__ wpart,
    const unsigned short* __restrict__ w2t, const float* __restrict__ g2b,
    float* gbuf2, int* bar, float* out) {
  __shared__ __align__(16) unsigned short vbf[512];
  __shared__ float vf[512];
  __shared__ float pl[4096];
  __shared__ float sl[256];
  __shared__ float wp[16][17];
  __shared__ float wsf[17];
  __shared__ float meanrow[32];
  int t = threadIdx.x, blk = blockIdx.x;
  int wave = t >> 6, lane = t & 63;

  {  // GCN1: 4 rows per wave; gbuf2[i] = dinv[i] * g[i]
    int wg = blk * 8 + wave;
#pragma unroll
    for (int rr = 0; rr < 4; rr++) {
      int i = wg * 4 + rr;
      int ci = min(cnt[i], CSR_CAP);
      float di = dinv[i];
      float a0 = 0.0f, a1 = 0.0f;
      for (int e = lane; e < ci; e += 64) {
        int s = csr[i * CSR_CAP + e];
        a0 += xs2[s];
        a1 += es2[s];
      }
      float f0 = (wsum64(a0) + di * xs2[i]) * di;
      float f1 = (wsum64(a1) + di * es2[i]) * di;
      if (lane < 16) {
        float gv = fmaxf(f0 * g1w[lane] + f1 * g1w[16 + lane] + g1b[lane], 0.0f);
        gbuf2[i * 16 + lane] = di * gv;
      }
    }
  }
  gridbar(bar, 1);
  {  // GCN2 gather: V_i = di*(sum gbuf2[s] + di*gbuf2[i]); 4 rows/wave
    int rowbase = blk * 32;
    int eq = lane >> 4, c = lane & 15;
#pragma unroll
    for (int rr = 0; rr < 4; rr++) {
      int il = wave * 4 + rr;
      int i = rowbase + il;
      int ci = min(cnt[i], CSR_CAP);
      float di = dinv[i];
      float acc = (eq == 0) ? di * gbuf2[i * 16 + c] : 0.0f;
      for (int e = eq; e < ci; e += 4) {
        int s = csr[i * CSR_CAP + e];
        acc += gbuf2[s * 16 + c];
      }
      acc *= di;
      acc += __shfl_xor(acc, 16, 64);
      acc += __shfl_xor(acc, 32, 64);
      if (eq == 0) {
        vf[il * 16 + c] = acc;
        vbf[il * 16 + c] = f2bf(acc);
      }
    }
  }
  __syncthreads();
  if (t < 272) {  // wstats reduce from per-block partials
    int bq = t / 17, k = t - bq * 17;
    float s = 0.0f;
    for (int b = bq; b < 256; b += 16) s += wpart[b * 17 + k];
    wp[bq][k] = s;
  }
  __syncthreads();
  if (t < 17) {
    float s = 0.0f;
#pragma unroll
    for (int q = 0; q < 16; q++) s += wp[q][t];
    wsf[t] = s;
  }
  __syncthreads();
  float myMean = 0.0f;
  if (t < 32) {
    float dot = 0.0f;
#pragma unroll
    for (int c = 0; c < 16; c++) dot += vf[t * 16 + c] * wsf[c];
    myMean = (dot + wsf[16]) * (1.0f / 8192.0f);
  }
  {  // scores via MFMA + direct sum-of-exp (|s| provably small)
    int quad = lane >> 4, n = lane & 15;
    int k8 = quad * 8;
    short8 za = {0, 0, 0, 0, 0, 0, 0, 0};
    short8 a1 = za, a2 = za;
    if (quad < 2) {
      a1 = *(const short8*)&vbf[n * 16 + k8];
      a2 = *(const short8*)&vbf[(16 + n) * 16 + k8];
    }
    float sacc[8];
#pragma unroll
    for (int q = 0; q < 8; q++) sacc[q] = 0.0f;
    int colb = wave * 1024 + n;
    for (int tp = 0; tp < 64; tp += 2) {
      int col1 = colb + tp * 16;
      int col2 = col1 + 16;
      short8 b1 = za, b2 = za;
      if (quad < 2) {
        b1 = *(const short8*)&w2t[col1 * 16 + k8];
        b2 = *(const short8*)&w2t[col2 * 16 + k8];
      }
      float bb1 = g2b[col1], bb2 = g2b[col2];
      float4v c1 = {bb1, bb1, bb1, bb1};
      float4v c2 = {bb2, bb2, bb2, bb2};
      float4v s11 = __builtin_amdgcn_mfma_f32_16x16x32_bf16(a1, b1, c1, 0, 0, 0);
      float4v s21 = __builtin_amdgcn_mfma_f32_16x16x32_bf16(a2, b1, c1, 0, 0, 0);
      float4v s12 = __builtin_amdgcn_mfma_f32_16x16x32_bf16(a1, b2, c2, 0, 0, 0);
      float4v s22 = __builtin_amdgcn_mfma_f32_16x16x32_bf16(a2, b2, c2, 0, 0, 0);
#pragma unroll
      for (int r = 0; r < 4; r++) {
        sacc[r]     += __expf(s11[r]) + __expf(s12[r]);
        sacc[4 + r] += __expf(s21[r]) + __expf(s22[r]);
      }
    }
#pragma unroll
    for (int q = 0; q < 8; q++) {
      int rl = (q >> 2) * 16 + quad * 4 + (q & 3);
      int cc = wave * 16 + n;
      pl[rl * 128 + cc] = sacc[q];
    }
  }
  __syncthreads();
  if (t < 256) {
    int r = t >> 3, seg = t & 7;
    int base = r * 128 + seg * 16;
    float ll = 0.0f;
#pragma unroll
    for (int i = 0; i < 16; i++) ll += pl[base + i];
    sl[r * 8 + seg] = ll;
  }
  __syncthreads();
  if (t < 32) {
    float ll = 0.0f;
#pragma unroll
    for (int i = 0; i < 8; i++) ll += sl[t * 8 + i];
    out[256 + blk * 32 + t] = myMean - __logf(ll);
  }
}

extern "C" void kernel_launch(void* const* d_in, const int* in_sizes, int n_in,
                              void* d_out, int out_size, void* d_ws, size_t ws_size,
                              hipStream_t stream) {
  const float* x     = (const float*)d_in[0];
  const float* x_msg = (const float*)d_in[1];
  const int*   edges = (const int*)d_in[2];
  const int*   action= (const int*)d_in[3];
  const float* c1w   = (const float*)d_in[4];
  const float* c1b   = (const float*)d_in[5];
  const float* c2w   = (const float*)d_in[6];
  const float* c2b   = (const float*)d_in[7];
  const float* fcw   = (const float*)d_in[8];
  const float* fcb   = (const float*)d_in[9];
  const float* muw   = (const float*)d_in[10];
  const float* mub   = (const float*)d_in[11];
  const float* msgw  = (const float*)d_in[12];
  const float* msgb  = (const float*)d_in[13];
  const float* g1w   = (const float*)d_in[14];
  const float* g1b   = (const float*)d_in[15];
  const float* g2w   = (const float*)d_in[16];
  const float* g2b   = (const float*)d_in[17];
  float* out = (float*)d_out;  // reference outputs are fp32

  float* ws     = (float*)d_ws;
  float* h1024  = ws;                    // 262144
  float* hidden = ws + 262144;           // 131072
  float* es2    = ws + 393216;           // 8192
  float* dinv   = ws + 401408;           // 8192
  float* xs2    = ws + 409600;           // 8192
  float* gbuf2  = ws + 417792;           // 131072
  float* wpart  = ws + 548864;           // 4352
  unsigned short* w2t = (unsigned short*)(ws + 553216);  // 131072 bf16
  int*   cnt    = (int*)(ws + 618752);   // 8192
  int*   csr    = (int*)(ws + 626944);   // 1048576
  int*   bar    = (int*)(ws + 1675520);  // 16

  k_init<<<33, 256, 0, stream>>>(action, cnt, bar, out);
  kA<<<NBLK, NTHR, 0, stream>>>(x, edges, c1w, c1b, c2w, c2b, g2w, g2b,
                                h1024, w2t, wpart, cnt, csr);
  kB<<<NBLK, NTHR, 0, stream>>>(cnt, x_msg, h1024, fcw, fcb, muw, mub, action,
                                msgw, msgb, hidden, dinv, xs2, es2, bar, out);
  kC<<<NBLK, NTHR, 0, stream>>>(cnt, csr, dinv, xs2, es2, g1w, g1b, wpart,
                                w2t, g2b, gbuf2, bar, out);
}